// Round 1
// baseline (520.540 us; speedup 1.0000x reference)
//
#include <hip/hip_runtime.h>
#include <hip/hip_bf16.h>
#include <hip/hip_cooperative_groups.h>

namespace cg = cooperative_groups;

#define THREADS 256

typedef __attribute__((ext_vector_type(8))) short bfrag;     // 8 bf16 = 4 VGPR
typedef __attribute__((ext_vector_type(4))) float f32x4;     // MFMA accumulator

__device__ inline unsigned short f2b(float v) {
    __hip_bfloat16 b = __float2bfloat16(v);
    return *reinterpret_cast<unsigned short*>(&b);
}
__device__ inline float b2f(unsigned short u) {
    return __uint_as_float(((unsigned)u) << 16);
}
__device__ inline float rdv(const void* p, int off, bool isbf) {
    return isbf ? b2f(((const unsigned short*)p)[off]) : ((const float*)p)[off];
}

struct InPtrs { const void* p[23]; };

// ---------------- single cooperative kernel: detect + prep + CSR build ----------------
// P0: zero deg, block 0 detects dtype -> flag
// P1: blocks 0..26 W->frag conversion, block 27 BN fold, blocks >=28 degree count
// P2a: per-256-node chunk totals -> bsum
// P2b: cross-chunk prefix + in-chunk scan -> pos, row_ptr
// P3: scatter edges into CSR
__global__ __launch_bounds__(256, 2) void coop_prep(
    InPtrs in, int* __restrict__ flag,
    unsigned short* __restrict__ Wl1, unsigned short* __restrict__ Wl2,
    unsigned short* __restrict__ WlR, unsigned short* __restrict__ Wl3,
    float* __restrict__ bnsc1, float* __restrict__ bnsh1,
    float* __restrict__ bnsc2, float* __restrict__ bnsh2,
    float* __restrict__ AS1f, float* __restrict__ AD1f,
    float* __restrict__ AS2f, float* __restrict__ AD2f,
    float* __restrict__ AS3f, float* __restrict__ AD3f, float* __restrict__ B3f,
    int* __restrict__ deg, int* __restrict__ bsum,
    int* __restrict__ row_ptr, int* __restrict__ pos, int* __restrict__ csr,
    const int* __restrict__ ei, int N, int E, int NB) {
    cg::grid_group grid = cg::this_grid();
    int b = blockIdx.x, tid = threadIdx.x, G = gridDim.x;
    __shared__ int sred[8];

    // ---- P0: zero deg; block 0 detects dtype ----
    for (int i = b * 256 + tid; i < N; i += G * 256) deg[i] = 0;
    if (b == 0) {
        const unsigned short* x = (const unsigned short*)in.p[0];
        int local = 0;
        for (int i = tid; i < 4096; i += 256) {
            unsigned ex = (x[i] >> 7) & 0xFF;
            if (ex == 0xFF || ex >= 134 || (ex > 0 && ex <= 100)) local++;
        }
#pragma unroll
        for (int o = 1; o < 64; o <<= 1) local += __shfl_xor(local, o, 64);
        if ((tid & 63) == 0) sred[tid >> 6] = local;
        __syncthreads();
        if (tid == 0)
            *flag = ((sred[0] + sred[1] + sred[2] + sred[3]) * 8 > 4096) ? 0 : 1;
    }
    grid.sync();

    // ---- P1: W conversion + BN fold + degree count ----
    if (b < 27) {
        bool isbf = (*flag != 0);
        const void* Wv; unsigned short* o; int cols, tt;
        if (b < 8)       { Wv = in.p[2];  o = Wl1; cols = 128; tt = b; }
        else if (b < 16) { Wv = in.p[6];  o = Wl2; cols = 128; tt = b - 8; }
        else if (b < 24) { Wv = in.p[14]; o = WlR; cols = 128; tt = b - 16; }
        else             { Wv = in.p[10]; o = Wl3; cols = 40;  tt = b - 24; }
        int id = tt * 256 + tid;
        int t = id >> 8, ks = (id >> 6) & 3, l = id & 63;
        int q = l >> 4, n = l & 15;
        int c = t * 16 + n;
#pragma unroll
        for (int j = 0; j < 8; ++j) {
            int k = ks * 32 + q * 8 + j;
            float v = (c < cols) ? rdv(Wv, k * cols + c, isbf) : 0.f;
            o[id * 8 + j] = f2b(v);
        }
    } else if (b == 27) {
        bool isbf = (*flag != 0);
        int c = tid;
        if (c < 128) {
            float s = rdv(in.p[15], c, isbf) * rsqrtf(rdv(in.p[18], c, isbf) + 1e-5f);
            bnsc1[c] = s;
            bnsh1[c] = rdv(in.p[16], c, isbf) - rdv(in.p[17], c, isbf) * s +
                       rdv(in.p[5], c, isbf) * s;
            AS1f[c] = rdv(in.p[3], c, isbf);
            AD1f[c] = rdv(in.p[4], c, isbf);
            AS2f[c] = rdv(in.p[7], c, isbf);
            AD2f[c] = rdv(in.p[8], c, isbf);
        } else {
            int d = c - 128;
            float s = rdv(in.p[19], d, isbf) * rsqrtf(rdv(in.p[22], d, isbf) + 1e-5f);
            bnsc2[d] = s;
            bnsh2[d] = rdv(in.p[20], d, isbf) - rdv(in.p[21], d, isbf) * s +
                       rdv(in.p[9], d, isbf) * s;
            if (d < 40) {
                AS3f[d] = rdv(in.p[11], d, isbf);
                AD3f[d] = rdv(in.p[12], d, isbf);
                B3f[d] = rdv(in.p[13], d, isbf);
            }
        }
    } else {
        int stride = (G - 28) * 256;
        for (int i = (b - 28) * 256 + tid; i < E + N; i += stride) {
            int d = (i < E) ? ei[E + i] : (i - E);
            atomicAdd(&deg[d], 1);
        }
    }
    grid.sync();

    // ---- P2a: per-chunk totals ----
    for (int cb = b; cb < NB; cb += G) {
        int idx = cb * 256 + tid;
        int v = (idx < N) ? deg[idx] : 0;
        int s = v;
#pragma unroll
        for (int o = 1; o < 64; o <<= 1) s += __shfl_xor(s, o, 64);
        if ((tid & 63) == 0) sred[tid >> 6] = s;
        __syncthreads();
        if (tid == 0) bsum[cb] = sred[0] + sred[1] + sred[2] + sred[3];
        __syncthreads();
    }
    grid.sync();

    // ---- P2b: cross-chunk prefix + in-chunk scan -> pos, row_ptr ----
    for (int cb = b; cb < NB; cb += G) {
        int acc = 0;
        for (int t = tid; t < cb; t += 256) acc += bsum[t];
#pragma unroll
        for (int o = 1; o < 64; o <<= 1) acc += __shfl_xor(acc, o, 64);
        if ((tid & 63) == 0) sred[tid >> 6] = acc;
        __syncthreads();
        int boff = sred[0] + sred[1] + sred[2] + sred[3];
        int idx = cb * 256 + tid;
        int v = (idx < N) ? deg[idx] : 0;
        int lane = tid & 63, wv = tid >> 6;
        int sc = v;
#pragma unroll
        for (int o = 1; o < 64; o <<= 1) {
            int t2 = __shfl_up(sc, o, 64);
            if (lane >= o) sc += t2;
        }
        if (lane == 63) sred[4 + wv] = sc;
        __syncthreads();
        int add = boff;
#pragma unroll
        for (int k = 0; k < 4; ++k) add += (k < wv) ? sred[4 + k] : 0;
        int excl = add + sc - v;
        if (idx < N) {
            pos[idx] = excl;
            row_ptr[idx + 1] = excl + v;
        }
        if (idx == 0) row_ptr[0] = 0;
        __syncthreads();
    }
    grid.sync();

    // ---- P3: scatter ----
    for (int i = b * 256 + tid; i < E + N; i += G * 256) {
        int s, d;
        if (i < E) { s = ei[i]; d = ei[E + i]; }
        else { s = i - E; d = s; }
        int p = atomicAdd(&pos[d], 1);
        csr[p] = s;
    }
}

// ---------------- MFMA GEMM: [N,128]bf16 @ [128,cols]bf16 (row-major) ----------------
template <int COLT, int HEADS, bool ES>
__global__ __launch_bounds__(256) void gemm_mfma(
    const unsigned short* __restrict__ A, const unsigned short* __restrict__ Wg,
    const float* __restrict__ as_f, const float* __restrict__ ad_f,
    unsigned short* __restrict__ out, int ldc, int cols,
    float* __restrict__ es, float* __restrict__ ed, int N) {
    __shared__ __align__(16) unsigned short Wls[COLT * 2048];
    int tid = threadIdx.x;
    {
        const float4* src = (const float4*)Wg;
        float4* dst = (float4*)Wls;
#pragma unroll
        for (int i = 0; i < COLT; ++i) dst[tid + i * 256] = src[tid + i * 256];
    }
    __syncthreads();
    int w = tid >> 6, lane = tid & 63;
    int n = lane & 15, q = lane >> 4;
    int row0 = blockIdx.x * 64 + w * 16;
    int ar = row0 + n; ar = ar < N ? ar : N - 1;   // clamp: OOB rows harmless
    f32x4 acc[COLT];
#pragma unroll
    for (int t = 0; t < COLT; ++t) acc[t] = (f32x4){0.f, 0.f, 0.f, 0.f};
    const unsigned short* arow = A + (size_t)ar * 128;
#pragma unroll
    for (int ks = 0; ks < 4; ++ks) {
        bfrag a = *reinterpret_cast<const bfrag*>(arow + ks * 32 + q * 8);
#pragma unroll
        for (int t = 0; t < COLT; ++t) {
            bfrag b = *reinterpret_cast<const bfrag*>(&Wls[((t * 4 + ks) * 64 + lane) * 8]);
            acc[t] = __builtin_amdgcn_mfma_f32_16x16x32_bf16(a, b, acc[t], 0, 0, 0);
        }
    }
    if (ES) {
        float asv[COLT], adv[COLT];
#pragma unroll
        for (int t = 0; t < COLT; ++t) {
            int c = t * 16 + n;
            asv[t] = (c < cols) ? as_f[c] : 0.f;
            adv[t] = (c < cols) ? ad_f[c] : 0.f;
        }
#pragma unroll
        for (int r = 0; r < 4; ++r) {
            float pe[HEADS], pd[HEADS];
#pragma unroll
            for (int h = 0; h < HEADS; ++h) { pe[h] = 0.f; pd[h] = 0.f; }
#pragma unroll
            for (int t = 0; t < COLT; ++t) {
                int h = (HEADS == 4) ? (t >> 1) : 0;
                pe[h] = fmaf(acc[t][r], asv[t], pe[h]);
                pd[h] = fmaf(acc[t][r], adv[t], pd[h]);
            }
#pragma unroll
            for (int h = 0; h < HEADS; ++h) {
#pragma unroll
                for (int o = 1; o < 16; o <<= 1) {
                    pe[h] += __shfl_xor(pe[h], o, 64);
                    pd[h] += __shfl_xor(pd[h], o, 64);
                }
            }
            int row = row0 + q * 4 + r;
            if (n == 0 && row < N) {
#pragma unroll
                for (int h = 0; h < HEADS; ++h) {
                    es[(size_t)row * HEADS + h] = pe[h];
                    ed[(size_t)row * HEADS + h] = pd[h];
                }
            }
        }
    }
#pragma unroll
    for (int t = 0; t < COLT; ++t) {
        int col = t * 16 + n;
        if (col < cols) {
#pragma unroll
            for (int r = 0; r < 4; ++r) {
                int row = row0 + q * 4 + r;
                if (row < N) out[(size_t)row * ldc + col] = f2b(acc[t][r]);
            }
        }
    }
}

// W1 + Wres in one pass (A read once, fp32 or bf16 directly); both outputs bf16
__global__ __launch_bounds__(256) void gemm_dual(
    const void* __restrict__ Ain, const int* __restrict__ flag,
    const unsigned short* __restrict__ Wg1, const unsigned short* __restrict__ WgR,
    const float* __restrict__ as_f, const float* __restrict__ ad_f,
    unsigned short* __restrict__ xwb, unsigned short* __restrict__ resb,
    float* __restrict__ es, float* __restrict__ ed, int N) {
    __shared__ __align__(16) unsigned short Wls[16 * 2048];
    int tid = threadIdx.x;
    {
        const float4* s1 = (const float4*)Wg1;
        const float4* s2 = (const float4*)WgR;
        float4* dst = (float4*)Wls;
#pragma unroll
        for (int i = 0; i < 8; ++i) dst[tid + i * 256] = s1[tid + i * 256];
#pragma unroll
        for (int i = 0; i < 8; ++i) dst[2048 + tid + i * 256] = s2[tid + i * 256];
    }
    bool isbf = (*flag != 0);
    __syncthreads();
    int w = tid >> 6, lane = tid & 63;
    int n = lane & 15, q = lane >> 4;
    int row0 = blockIdx.x * 64 + w * 16;
    int ar = row0 + n; ar = ar < N ? ar : N - 1;
    bfrag a[4];
    if (isbf) {
        const unsigned short* arow = (const unsigned short*)Ain + (size_t)ar * 128;
#pragma unroll
        for (int ks = 0; ks < 4; ++ks)
            a[ks] = *reinterpret_cast<const bfrag*>(arow + ks * 32 + q * 8);
    } else {
        const float* arow = (const float*)Ain + (size_t)ar * 128;
#pragma unroll
        for (int ks = 0; ks < 4; ++ks) {
            float4 f0 = *reinterpret_cast<const float4*>(arow + ks * 32 + q * 8);
            float4 f1 = *reinterpret_cast<const float4*>(arow + ks * 32 + q * 8 + 4);
            bfrag t;
            t[0] = (short)f2b(f0.x); t[1] = (short)f2b(f0.y);
            t[2] = (short)f2b(f0.z); t[3] = (short)f2b(f0.w);
            t[4] = (short)f2b(f1.x); t[5] = (short)f2b(f1.y);
            t[6] = (short)f2b(f1.z); t[7] = (short)f2b(f1.w);
            a[ks] = t;
        }
    }
    f32x4 acc[16];
#pragma unroll
    for (int t = 0; t < 16; ++t) acc[t] = (f32x4){0.f, 0.f, 0.f, 0.f};
#pragma unroll
    for (int ks = 0; ks < 4; ++ks) {
#pragma unroll
        for (int t = 0; t < 8; ++t) {
            bfrag b = *reinterpret_cast<const bfrag*>(&Wls[((t * 4 + ks) * 64 + lane) * 8]);
            acc[t] = __builtin_amdgcn_mfma_f32_16x16x32_bf16(a[ks], b, acc[t], 0, 0, 0);
        }
#pragma unroll
        for (int t = 0; t < 8; ++t) {
            bfrag b = *reinterpret_cast<const bfrag*>(&Wls[16384 + ((t * 4 + ks) * 64 + lane) * 8]);
            acc[8 + t] = __builtin_amdgcn_mfma_f32_16x16x32_bf16(a[ks], b, acc[8 + t], 0, 0, 0);
        }
    }
    float asv[8], adv[8];
#pragma unroll
    for (int t = 0; t < 8; ++t) {
        int c = t * 16 + n;
        asv[t] = as_f[c];
        adv[t] = ad_f[c];
    }
#pragma unroll
    for (int r = 0; r < 4; ++r) {
        float pe[4] = {0.f, 0.f, 0.f, 0.f}, pd[4] = {0.f, 0.f, 0.f, 0.f};
#pragma unroll
        for (int t = 0; t < 8; ++t) {
            int h = t >> 1;
            pe[h] = fmaf(acc[t][r], asv[t], pe[h]);
            pd[h] = fmaf(acc[t][r], adv[t], pd[h]);
        }
#pragma unroll
        for (int h = 0; h < 4; ++h) {
#pragma unroll
            for (int o = 1; o < 16; o <<= 1) {
                pe[h] += __shfl_xor(pe[h], o, 64);
                pd[h] += __shfl_xor(pd[h], o, 64);
            }
        }
        int row = row0 + q * 4 + r;
        if (n == 0 && row < N) {
#pragma unroll
            for (int h = 0; h < 4; ++h) {
                es[(size_t)row * 4 + h] = pe[h];
                ed[(size_t)row * 4 + h] = pd[h];
            }
        }
    }
#pragma unroll
    for (int t = 0; t < 8; ++t) {
        int col = t * 16 + n;
#pragma unroll
        for (int r = 0; r < 4; ++r) {
            int row = row0 + q * 4 + r;
            if (row < N) {
                xwb[(size_t)row * 128 + col] = f2b(acc[t][r]);
                resb[(size_t)row * 128 + col] = f2b(acc[8 + t][r]);
            }
        }
    }
}

// ---------------- agg layers 1-2 + fused BN/bias/residual/ELU ----------------
__global__ __launch_bounds__(256) void agg128_fused(
    const unsigned short* __restrict__ xwb, const float* __restrict__ es,
    const float* __restrict__ ed, const int* __restrict__ row_ptr,
    const int* __restrict__ csr, const float* __restrict__ bnsc,
    const float* __restrict__ bnsh, const unsigned short* __restrict__ resb,
    unsigned short* __restrict__ outb, int N) {
    int w = threadIdx.x >> 6, lane = threadIdx.x & 63;
    int node = blockIdx.x * 4 + w;
    if (node >= N) return;
    int h = lane >> 4;
    int c0 = lane * 2;
    float edl = ed[node * 4 + h];
    int start = __builtin_amdgcn_readfirstlane(row_ptr[node]);
    int end = __builtin_amdgcn_readfirstlane(row_ptr[node + 1]);
    float den = 0.f, a0 = 0.f, a1 = 0.f;
    for (int jb = start; jb < end; jb += 16) {
        int su[16];
#pragma unroll
        for (int u = 0; u < 16; ++u) {
            int idx = jb + u;
            idx = idx < end - 1 ? idx : end - 1;
            su[u] = csr[idx];                       // uniform addr -> s_load
        }
        unsigned uu[16];
        float ev[16];
#pragma unroll
        for (int u = 0; u < 16; ++u) {
            uu[u] = *(const unsigned*)(xwb + (size_t)su[u] * 128 + c0);
            ev[u] = es[su[u] * 4 + h];
        }
#pragma unroll
        for (int u = 0; u < 16; ++u) {
            float e = ev[u] + edl;
            e = e > 0.f ? e : 0.2f * e;
            float wg = __expf(e);
            wg = (jb + u < end) ? wg : 0.f;         // uniform cond, branch-free
            den += wg;
            a0 = fmaf(wg, __uint_as_float(uu[u] << 16), a0);
            a1 = fmaf(wg, __uint_as_float(uu[u] & 0xffff0000u), a1);
        }
    }
    float inv = 1.f / den;
    float2 sc = *(const float2*)(bnsc + c0);
    float2 sh = *(const float2*)(bnsh + c0);
    unsigned ur = *(const unsigned*)(resb + (size_t)node * 128 + c0);
    float v0 = fmaf(a0 * inv, sc.x, sh.x) + __uint_as_float(ur << 16);
    float v1 = fmaf(a1 * inv, sc.y, sh.y) + __uint_as_float(ur & 0xffff0000u);
    v0 = v0 > 0.f ? v0 : expm1f(v0);
    v1 = v1 > 0.f ? v1 : expm1f(v1);
    unsigned pk = (unsigned)f2b(v0) | ((unsigned)f2b(v1) << 16);
    *(unsigned*)(outb + (size_t)node * 128 + c0) = pk;
}

// ---------------- layer-3 agg (H=1, 40ch) ----------------
__global__ __launch_bounds__(256) void agg40_kernel(
    const unsigned short* __restrict__ xw3b, const float* __restrict__ es3,
    const float* __restrict__ ed3, const int* __restrict__ row_ptr,
    const int* __restrict__ csr, const float* __restrict__ b3,
    void* __restrict__ out, const int* __restrict__ flag, int N) {
    int w = threadIdx.x >> 6, lane = threadIdx.x & 63;
    int node = blockIdx.x * 4 + w;
    if (node >= N) return;
    int i16 = lane & 15;
    int g = lane >= 40 ? 2 : (lane >= 20 ? 1 : 0);
    int cp = lane - g * 20;
    int c0 = cp * 2; c0 = c0 > 38 ? 38 : c0;
    float edl = ed3[node];
    int start = row_ptr[node], end = row_ptr[node + 1];
    float den = 0.f, a0 = 0.f, a1 = 0.f;
    for (int jb = start; jb < end; jb += 16) {
        int cnt = end - jb; cnt = cnt < 16 ? cnt : 16;
        int sv = csr[jb + (i16 < cnt ? i16 : 0)];
        unsigned uu[6];
#pragma unroll
        for (int t = 0; t < 6; ++t) {
            int slot = 3 * t + g; slot = slot < 15 ? slot : 15;
            int s = __shfl(sv, slot, 64);
            uu[t] = *(const unsigned*)(xw3b + (size_t)s * 40 + c0);
        }
        float wgl = 0.f;
        if (i16 < cnt) {
            float e = es3[sv] + edl;
            e = e > 0.f ? e : 0.2f * e;
            wgl = __expf(e);
        }
        float d = wgl;
        d += __shfl_xor(d, 1, 64);
        d += __shfl_xor(d, 2, 64);
        d += __shfl_xor(d, 4, 64);
        d += __shfl_xor(d, 8, 64);
        den += d;
#pragma unroll
        for (int t = 0; t < 6; ++t) {
            int slot = 3 * t + g;
            int sl = slot < 15 ? slot : 15;
            float wg = __shfl(wgl, sl, 64);
            if (slot >= cnt) wg = 0.f;
            a0 = fmaf(wg, __uint_as_float(uu[t] << 16), a0);
            a1 = fmaf(wg, __uint_as_float(uu[t] & 0xffff0000u), a1);
        }
    }
    float t0 = __shfl(a0, (lane + 20) & 63, 64);
    float t1 = __shfl(a0, (lane + 40) & 63, 64);
    float u0 = __shfl(a1, (lane + 20) & 63, 64);
    float u1 = __shfl(a1, (lane + 40) & 63, 64);
    a0 += t0 + t1;
    a1 += u0 + u1;
    if (lane < 20) {
        float inv = 1.f / den;
        float v0 = a0 * inv + b3[c0];
        float v1 = a1 * inv + b3[c0 + 1];
        size_t eoff = (size_t)node * 40 + c0;
        if (*flag) {
            unsigned pk = (unsigned)f2b(v0) | ((unsigned)f2b(v1) << 16);
            *(unsigned*)((unsigned short*)out + eoff) = pk;
        } else {
            *(float2*)((float*)out + eoff) = make_float2(v0, v1);
        }
    }
}

extern "C" void kernel_launch(void* const* d_in, const int* in_sizes, int n_in,
                              void* d_out, int out_size, void* d_ws, size_t ws_size,
                              hipStream_t stream) {
    (void)n_in; (void)out_size; (void)ws_size;
    const int N = in_sizes[0] / 128;
    const int E = in_sizes[1] / 2;
    const int EPN = E + N;
    const int NB = (N + 255) / 256;
    char* base = (char*)d_ws;
    size_t off = 0;
    auto alloc = [&](size_t bytes) -> char* {
        char* p = base + off;
        off = (off + bytes + 255) & ~(size_t)255;
        return p;
    };
    int* flag = (int*)alloc(4);
    int* deg = (int*)alloc((size_t)N * 4);
    int* row_ptr = (int*)alloc((size_t)(N + 1) * 4);
    int* pos = (int*)alloc((size_t)N * 4);
    int* bsum = (int*)alloc((size_t)NB * 4);
    int* csr = (int*)alloc((size_t)EPN * 4);
    float* bnsc1 = (float*)alloc(512); float* bnsh1 = (float*)alloc(512);
    float* bnsc2 = (float*)alloc(512); float* bnsh2 = (float*)alloc(512);
    float* AS1f = (float*)alloc(512); float* AD1f = (float*)alloc(512);
    float* AS2f = (float*)alloc(512); float* AD2f = (float*)alloc(512);
    float* AS3f = (float*)alloc(256); float* AD3f = (float*)alloc(256);
    float* B3f = (float*)alloc(256);
    unsigned short* Wl1 = (unsigned short*)alloc(32768);
    unsigned short* Wl2 = (unsigned short*)alloc(32768);
    unsigned short* WlR = (unsigned short*)alloc(32768);
    unsigned short* Wl3 = (unsigned short*)alloc(12288);
    unsigned short* xwb = (unsigned short*)alloc((size_t)N * 128 * 2);  // also xw3
    unsigned short* h1b = (unsigned short*)alloc((size_t)N * 128 * 2);
    unsigned short* resb = (unsigned short*)alloc((size_t)N * 128 * 2); // later h2b
    float* es = (float*)alloc((size_t)N * 4 * 4);   // [node*4+h]
    float* ed = (float*)alloc((size_t)N * 4 * 4);

    const int* ei = (const int*)d_in[1];

    InPtrs ip;
    for (int t = 0; t < 23; t++) ip.p[t] = d_in[t];

    // ---- single cooperative dispatch: detect + prep + full CSR build ----
    // 512 blocks x 256 threads; __launch_bounds__(256,2) => >=2 blocks/CU
    // guaranteed co-resident on 256 CUs.
    int Nv = N, Ev = E, NBv = NB;
    const int* eip = ei;
    void* cargs[] = {&ip, &flag, &Wl1, &Wl2, &WlR, &Wl3,
                     &bnsc1, &bnsh1, &bnsc2, &bnsh2,
                     &AS1f, &AD1f, &AS2f, &AD2f, &AS3f, &AD3f, &B3f,
                     &deg, &bsum, &row_ptr, &pos, &csr, &eip, &Nv, &Ev, &NBv};
    hipLaunchCooperativeKernel((const void*)coop_prep, dim3(512), dim3(256),
                               cargs, 0, stream);

    int gemmGrid = (N + 63) / 64;
    int aggGrid = (N + 3) / 4;

    // layer 1 (W1 + Wres fused GEMM, direct fp32/bf16 A read)
    gemm_dual<<<gemmGrid, 256, 0, stream>>>(d_in[0], flag, Wl1, WlR, AS1f, AD1f,
                                            xwb, resb, es, ed, N);
    agg128_fused<<<aggGrid, 256, 0, stream>>>(xwb, es, ed, row_ptr, csr,
                                              bnsc1, bnsh1, resb, h1b, N);
    // layer 2
    gemm_mfma<8, 4, true><<<gemmGrid, 256, 0, stream>>>(
        h1b, Wl2, AS2f, AD2f, xwb, 128, 128, es, ed, N);
    unsigned short* h2b = resb;  // resb free after layer-1 agg
    agg128_fused<<<aggGrid, 256, 0, stream>>>(xwb, es, ed, row_ptr, csr,
                                              bnsc2, bnsh2, h1b, h2b, N);
    // layer 3
    gemm_mfma<3, 1, true><<<gemmGrid, 256, 0, stream>>>(
        h2b, Wl3, AS3f, AD3f, xwb, 40, 40, es, ed, N);
    agg40_kernel<<<aggGrid, 256, 0, stream>>>(xwb, es, ed, row_ptr, csr, B3f,
                                              d_out, flag, N);
}

// Round 2
// 308.799 us; speedup vs baseline: 1.6857x; 1.6857x over previous
//
#include <hip/hip_runtime.h>
#include <hip/hip_bf16.h>

#define THREADS 256

typedef __attribute__((ext_vector_type(8))) short bfrag;     // 8 bf16 = 4 VGPR
typedef __attribute__((ext_vector_type(4))) float f32x4;     // MFMA accumulator

__device__ inline unsigned short f2b(float v) {
    __hip_bfloat16 b = __float2bfloat16(v);
    return *reinterpret_cast<unsigned short*>(&b);
}
__device__ inline float b2f(unsigned short u) {
    return __uint_as_float(((unsigned)u) << 16);
}
__device__ inline float rdv(const void* p, int off, bool isbf) {
    return isbf ? b2f(((const unsigned short*)p)[off]) : ((const float*)p)[off];
}

struct InPtrs { const void* p[23]; };

// ---------------- fused prep: dtype detect (per-block), W->frag-order (+folded
// es/ed columns), BN fold, degree count, x conversion ----------------
// blocks 0..8   : W1 tiles 0..8 (tile 8 = folded es/ed columns 128..135)
// blocks 9..17  : W2 tiles 0..8 (tile 8 = folded es/ed columns)
// blocks 18..25 : Wres tiles 0..7
// blocks 26..28 : W3 tiles 0..2 (cols 40,41 inside tile 2 = folded es/ed)
// block  29     : BN folds + B3 + publish flag
// blocks 30..30+CB-1 : degree count
// blocks >=30+CB     : x fp32->bf16 conversion (skipped if input is bf16)
__global__ void prep_kernel(InPtrs in, int* __restrict__ flag,
                            unsigned short* __restrict__ Wl1, unsigned short* __restrict__ Wl2,
                            unsigned short* __restrict__ WlR, unsigned short* __restrict__ Wl3,
                            float* __restrict__ bnsc1, float* __restrict__ bnsh1,
                            float* __restrict__ bnsc2, float* __restrict__ bnsh2,
                            float* __restrict__ B3f, unsigned short* __restrict__ xb,
                            int N, const int* __restrict__ ei, int* __restrict__ deg,
                            int E, int CB) {
    int b = blockIdx.x, tid = threadIdx.x;
    __shared__ int sred[4];
    bool isbf = false;
    bool needf = (b < 30) || (b >= 30 + CB);
    if (needf) {
        // local dtype detect over first 4096 shorts (L2-broadcast, ~free)
        const unsigned short* x = (const unsigned short*)in.p[0];
        int local = 0;
        for (int i = tid; i < 4096; i += 256) {
            unsigned ex = (x[i] >> 7) & 0xFF;
            if (ex == 0xFF || ex >= 134 || (ex > 0 && ex <= 100)) local++;
        }
#pragma unroll
        for (int o = 1; o < 64; o <<= 1) local += __shfl_xor(local, o, 64);
        if ((tid & 63) == 0) sred[tid >> 6] = local;
        __syncthreads();
        int cnt = sred[0] + sred[1] + sred[2] + sred[3];
        isbf = !(cnt * 8 > 4096);
    }
    if (b < 29) {
        const void *Wv, *asp = 0, *adp = 0; unsigned short* o; int cols, C = 0, FH = 0, tt;
        if (b < 9)       { Wv = in.p[2];  asp = in.p[3];  adp = in.p[4];  o = Wl1; cols = 128; C = 32; FH = 4; tt = b; }
        else if (b < 18) { Wv = in.p[6];  asp = in.p[7];  adp = in.p[8];  o = Wl2; cols = 128; C = 32; FH = 4; tt = b - 9; }
        else if (b < 26) { Wv = in.p[14];                                 o = WlR; cols = 128;                 tt = b - 18; }
        else             { Wv = in.p[10]; asp = in.p[11]; adp = in.p[12]; o = Wl3; cols = 40;  C = 40; FH = 1; tt = b - 26; }
        int id = tt * 256 + tid;
        int ks = (id >> 6) & 3, l = id & 63;
        int q = l >> 4, n = l & 15;
        int c = tt * 16 + n;
#pragma unroll
        for (int j = 0; j < 8; ++j) {
            int k = ks * 32 + q * 8 + j;
            float v = 0.f;
            if (c < cols) {
                v = rdv(Wv, k * cols + c, isbf);
            } else if (FH && c < cols + 2 * FH) {
                // folded attention column: Wes[k,h] = sum_c W[k,h*C+c]*a[h,c]
                int dn = c - cols;
                int h = dn < FH ? dn : dn - FH;
                const void* av = dn < FH ? asp : adp;
                float s = 0.f;
                for (int cc = 0; cc < C; ++cc)
                    s += rdv(Wv, k * cols + h * C + cc, isbf) * rdv(av, h * C + cc, isbf);
                v = s;
            }
            o[id * 8 + j] = f2b(v);
        }
    } else if (b == 29) {
        int c = tid;
        if (c < 128) {
            float s = rdv(in.p[15], c, isbf) * rsqrtf(rdv(in.p[18], c, isbf) + 1e-5f);
            bnsc1[c] = s;
            bnsh1[c] = rdv(in.p[16], c, isbf) - rdv(in.p[17], c, isbf) * s +
                       rdv(in.p[5], c, isbf) * s;
        } else {
            int d = c - 128;
            float s = rdv(in.p[19], d, isbf) * rsqrtf(rdv(in.p[22], d, isbf) + 1e-5f);
            bnsc2[d] = s;
            bnsh2[d] = rdv(in.p[20], d, isbf) - rdv(in.p[21], d, isbf) * s +
                       rdv(in.p[9], d, isbf) * s;
            if (d < 40) B3f[d] = rdv(in.p[13], d, isbf);
        }
        if (tid == 0) *flag = isbf ? 1 : 0;
    } else if (b < 30 + CB) {
        int i = (b - 30) * 256 + tid;
        if (i < E + N) {
            int d = (i < E) ? ei[E + i] : (i - E);
            atomicAdd(&deg[d], 1);
        }
    } else {
        if (isbf) return;  // bf16 path: gemm reads d_in[0] raw
        const float* xf = (const float*)in.p[0];
        int total = N * 128;
        int stride = (gridDim.x - 30 - CB) * 256;
        for (int i = (b - 30 - CB) * 256 + tid; i < total; i += stride)
            xb[i] = f2b(xf[i]);
    }
}

// ---------------- single-dispatch CSR scan: decoupled lookback ----------------
// look[b] packs (status<<32)|value: status 0=invalid, 1=aggregate, 2=prefix.
// Value travels inside the atomic word -> no separate fence needed.
__global__ __launch_bounds__(256) void scan_kernel(
    const int* __restrict__ deg, unsigned long long* __restrict__ look,
    int* __restrict__ row_ptr, int* __restrict__ pos, int N) {
    int b = blockIdx.x, tid = threadIdx.x;
    int lane = tid & 63, wv = tid >> 6;
    __shared__ int ws[4];
    __shared__ int s_off;
    int idx = b * 256 + tid;
    int v = (idx < N) ? deg[idx] : 0;
    int sc = v;
#pragma unroll
    for (int o = 1; o < 64; o <<= 1) {
        int t = __shfl_up(sc, o, 64);
        if (lane >= o) sc += t;
    }
    if (lane == 63) ws[wv] = sc;
    __syncthreads();
    int tot = ws[0] + ws[1] + ws[2] + ws[3];
    if (tid == 0)
        atomicExch(&look[b], (1ULL << 32) | (unsigned)tot);  // publish aggregate
    if (wv == 0) {
        int run = 0;
        if (b > 0) {
            int base = b - 1;
            for (;;) {
                int i = base - lane;
                unsigned long long st = (i >= 0) ? atomicAdd(&look[i], 0ULL)
                                                 : (2ULL << 32);  // OOB = prefix 0
                int status = (int)(st >> 32);
                int val = (int)(st & 0xffffffffULL);
                unsigned long long bp = __ballot(status == 2);
                unsigned long long bz = __ballot(status == 0);
                int fp = bp ? (__ffsll(bp) - 1) : 64;
                int fz = bz ? (__ffsll(bz) - 1) : 64;
                if (fz < fp) continue;          // gap before nearest prefix: retry
                int contrib = (lane <= fp) ? val : 0;  // fp==64 -> take all 64
#pragma unroll
                for (int o = 1; o < 64; o <<= 1) contrib += __shfl_xor(contrib, o, 64);
                run += contrib;
                if (fp < 64) break;
                base -= 64;
            }
        }
        if (lane == 0) {
            s_off = run;
            atomicExch(&look[b], (2ULL << 32) | (unsigned)(run + tot));  // prefix
        }
    }
    __syncthreads();
    int add = s_off;
#pragma unroll
    for (int k = 0; k < 4; ++k) add += (k < wv) ? ws[k] : 0;
    int excl = add + sc - v;
    if (idx < N) {
        pos[idx] = excl;
        row_ptr[idx + 1] = excl + v;
    }
    if (idx == 0) row_ptr[0] = 0;
}

__global__ void scatter_kernel(const int* __restrict__ ei, int* __restrict__ pos,
                               int* __restrict__ csr, int E, int N) {
    int e = blockIdx.x * THREADS + threadIdx.x;
    if (e >= E + N) return;
    int s, d;
    if (e < E) { s = ei[e]; d = ei[E + e]; }
    else { s = e - E; d = s; }
    int p = atomicAdd(&pos[d], 1);
    csr[p] = s;
}

// ---------------- MFMA GEMM: [N,128]bf16 @ [128,cols+fold]bf16 ----------------
// es/ed come out of MFMA tile TE (folded weight columns) -> no shfl epilogue.
template <int COLT, int HEADS, int ESCOL>
__global__ __launch_bounds__(256) void gemm_mfma(
    const unsigned short* __restrict__ A, const unsigned short* __restrict__ Wg,
    unsigned short* __restrict__ out, int ldc, int cols,
    float* __restrict__ es, float* __restrict__ ed, int N) {
    __shared__ __align__(16) unsigned short Wls[COLT * 2048];
    int tid = threadIdx.x;
    {
        const float4* src = (const float4*)Wg;
        float4* dst = (float4*)Wls;
#pragma unroll
        for (int i = 0; i < COLT; ++i) dst[tid + i * 256] = src[tid + i * 256];
    }
    __syncthreads();
    int w = tid >> 6, lane = tid & 63;
    int n = lane & 15, q = lane >> 4;
    int row0 = blockIdx.x * 64 + w * 16;
    int ar = row0 + n; ar = ar < N ? ar : N - 1;   // clamp: OOB rows harmless
    f32x4 acc[COLT];
#pragma unroll
    for (int t = 0; t < COLT; ++t) acc[t] = (f32x4){0.f, 0.f, 0.f, 0.f};
    const unsigned short* arow = A + (size_t)ar * 128;
#pragma unroll
    for (int ks = 0; ks < 4; ++ks) {
        bfrag a = *reinterpret_cast<const bfrag*>(arow + ks * 32 + q * 8);
#pragma unroll
        for (int t = 0; t < COLT; ++t) {
            bfrag b = *reinterpret_cast<const bfrag*>(&Wls[((t * 4 + ks) * 64 + lane) * 8]);
            acc[t] = __builtin_amdgcn_mfma_f32_16x16x32_bf16(a, b, acc[t], 0, 0, 0);
        }
    }
    constexpr int TE = ESCOL >> 4, NE = ESCOL & 15;
    int dn = n - NE;
#pragma unroll
    for (int r = 0; r < 4; ++r) {
        int row = row0 + q * 4 + r;
        if (row < N) {
            if (dn >= 0 && dn < HEADS) es[(size_t)row * HEADS + dn] = acc[TE][r];
            else if (dn >= HEADS && dn < 2 * HEADS)
                ed[(size_t)row * HEADS + (dn - HEADS)] = acc[TE][r];
        }
    }
#pragma unroll
    for (int t = 0; t < COLT; ++t) {
        int col = t * 16 + n;
        if (col < cols) {
#pragma unroll
            for (int r = 0; r < 4; ++r) {
                int row = row0 + q * 4 + r;
                if (row < N) out[(size_t)row * ldc + col] = f2b(acc[t][r]);
            }
        }
    }
}

// W1 + Wres in one pass (A read once); es/ed from folded tile 8 of Wl1 (global)
__global__ __launch_bounds__(256) void gemm_dual(
    const unsigned short* __restrict__ Araw, const unsigned short* __restrict__ Acvt,
    const int* __restrict__ flag,
    const unsigned short* __restrict__ Wg1, const unsigned short* __restrict__ WgR,
    unsigned short* __restrict__ xwb, unsigned short* __restrict__ resb,
    float* __restrict__ es, float* __restrict__ ed, int N) {
    __shared__ __align__(16) unsigned short Wls[16 * 2048];
    int tid = threadIdx.x;
    {
        const float4* s1 = (const float4*)Wg1;
        const float4* s2 = (const float4*)WgR;
        float4* dst = (float4*)Wls;
#pragma unroll
        for (int i = 0; i < 8; ++i) dst[tid + i * 256] = s1[tid + i * 256];
#pragma unroll
        for (int i = 0; i < 8; ++i) dst[2048 + tid + i * 256] = s2[tid + i * 256];
    }
    const unsigned short* A = (*flag) ? Araw : Acvt;
    __syncthreads();
    int w = tid >> 6, lane = tid & 63;
    int n = lane & 15, q = lane >> 4;
    int row0 = blockIdx.x * 64 + w * 16;
    int ar = row0 + n; ar = ar < N ? ar : N - 1;
    f32x4 acc[16], accE;
#pragma unroll
    for (int t = 0; t < 16; ++t) acc[t] = (f32x4){0.f, 0.f, 0.f, 0.f};
    accE = (f32x4){0.f, 0.f, 0.f, 0.f};
    const unsigned short* arow = A + (size_t)ar * 128;
#pragma unroll
    for (int ks = 0; ks < 4; ++ks) {
        bfrag a = *reinterpret_cast<const bfrag*>(arow + ks * 32 + q * 8);
#pragma unroll
        for (int t = 0; t < 8; ++t) {
            bfrag b = *reinterpret_cast<const bfrag*>(&Wls[((t * 4 + ks) * 64 + lane) * 8]);
            acc[t] = __builtin_amdgcn_mfma_f32_16x16x32_bf16(a, b, acc[t], 0, 0, 0);
        }
        // folded es/ed tile read straight from global (L2-hot broadcast)
        bfrag be = *reinterpret_cast<const bfrag*>(Wg1 + ((size_t)(32 + ks) * 64 + lane) * 8);
        accE = __builtin_amdgcn_mfma_f32_16x16x32_bf16(a, be, accE, 0, 0, 0);
#pragma unroll
        for (int t = 0; t < 8; ++t) {
            bfrag b = *reinterpret_cast<const bfrag*>(&Wls[16384 + ((t * 4 + ks) * 64 + lane) * 8]);
            acc[8 + t] = __builtin_amdgcn_mfma_f32_16x16x32_bf16(a, b, acc[8 + t], 0, 0, 0);
        }
    }
#pragma unroll
    for (int r = 0; r < 4; ++r) {
        int row = row0 + q * 4 + r;
        if (row < N) {
            if (n < 4) es[(size_t)row * 4 + n] = accE[r];
            else if (n < 8) ed[(size_t)row * 4 + (n - 4)] = accE[r];
        }
    }
#pragma unroll
    for (int t = 0; t < 8; ++t) {
        int col = t * 16 + n;
#pragma unroll
        for (int r = 0; r < 4; ++r) {
            int row = row0 + q * 4 + r;
            if (row < N) {
                xwb[(size_t)row * 128 + col] = f2b(acc[t][r]);
                resb[(size_t)row * 128 + col] = f2b(acc[8 + t][r]);
            }
        }
    }
}

// ---------------- agg layers 1-2 + fused BN/bias/residual/ELU ----------------
__global__ __launch_bounds__(256) void agg128_fused(
    const unsigned short* __restrict__ xwb, const float* __restrict__ es,
    const float* __restrict__ ed, const int* __restrict__ row_ptr,
    const int* __restrict__ csr, const float* __restrict__ bnsc,
    const float* __restrict__ bnsh, const unsigned short* __restrict__ resb,
    unsigned short* __restrict__ outb, int N) {
    int w = threadIdx.x >> 6, lane = threadIdx.x & 63;
    int node = blockIdx.x * 4 + w;
    if (node >= N) return;
    int h = lane >> 4;
    int c0 = lane * 2;
    float edl = ed[node * 4 + h];
    int start = __builtin_amdgcn_readfirstlane(row_ptr[node]);
    int end = __builtin_amdgcn_readfirstlane(row_ptr[node + 1]);
    float den = 0.f, a0 = 0.f, a1 = 0.f;
    for (int jb = start; jb < end; jb += 16) {
        int su[16];
#pragma unroll
        for (int u = 0; u < 16; ++u) {
            int idx = jb + u;
            idx = idx < end - 1 ? idx : end - 1;
            su[u] = csr[idx];                       // uniform addr -> s_load
        }
        unsigned uu[16];
        float ev[16];
#pragma unroll
        for (int u = 0; u < 16; ++u) {
            uu[u] = *(const unsigned*)(xwb + (size_t)su[u] * 128 + c0);
            ev[u] = es[su[u] * 4 + h];
        }
#pragma unroll
        for (int u = 0; u < 16; ++u) {
            float e = ev[u] + edl;
            e = e > 0.f ? e : 0.2f * e;
            float wg = __expf(e);
            wg = (jb + u < end) ? wg : 0.f;         // uniform cond, branch-free
            den += wg;
            a0 = fmaf(wg, __uint_as_float(uu[u] << 16), a0);
            a1 = fmaf(wg, __uint_as_float(uu[u] & 0xffff0000u), a1);
        }
    }
    float inv = 1.f / den;
    float2 sc = *(const float2*)(bnsc + c0);
    float2 sh = *(const float2*)(bnsh + c0);
    unsigned ur = *(const unsigned*)(resb + (size_t)node * 128 + c0);
    float v0 = fmaf(a0 * inv, sc.x, sh.x) + __uint_as_float(ur << 16);
    float v1 = fmaf(a1 * inv, sc.y, sh.y) + __uint_as_float(ur & 0xffff0000u);
    v0 = v0 > 0.f ? v0 : expm1f(v0);
    v1 = v1 > 0.f ? v1 : expm1f(v1);
    unsigned pk = (unsigned)f2b(v0) | ((unsigned)f2b(v1) << 16);
    *(unsigned*)(outb + (size_t)node * 128 + c0) = pk;
}

// ---------------- layer-3 agg (H=1, 40ch) ----------------
__global__ __launch_bounds__(256) void agg40_kernel(
    const unsigned short* __restrict__ xw3b, const float* __restrict__ es3,
    const float* __restrict__ ed3, const int* __restrict__ row_ptr,
    const int* __restrict__ csr, const float* __restrict__ b3,
    void* __restrict__ out, const int* __restrict__ flag, int N) {
    int w = threadIdx.x >> 6, lane = threadIdx.x & 63;
    int node = blockIdx.x * 4 + w;
    if (node >= N) return;
    int i16 = lane & 15;
    int g = lane >= 40 ? 2 : (lane >= 20 ? 1 : 0);
    int cp = lane - g * 20;
    int c0 = cp * 2; c0 = c0 > 38 ? 38 : c0;
    float edl = ed3[node];
    int start = row_ptr[node], end = row_ptr[node + 1];
    float den = 0.f, a0 = 0.f, a1 = 0.f;
    for (int jb = start; jb < end; jb += 16) {
        int cnt = end - jb; cnt = cnt < 16 ? cnt : 16;
        int sv = csr[jb + (i16 < cnt ? i16 : 0)];
        unsigned uu[6];
#pragma unroll
        for (int t = 0; t < 6; ++t) {
            int slot = 3 * t + g; slot = slot < 15 ? slot : 15;
            int s = __shfl(sv, slot, 64);
            uu[t] = *(const unsigned*)(xw3b + (size_t)s * 40 + c0);
        }
        float wgl = 0.f;
        if (i16 < cnt) {
            float e = es3[sv] + edl;
            e = e > 0.f ? e : 0.2f * e;
            wgl = __expf(e);
        }
        float d = wgl;
        d += __shfl_xor(d, 1, 64);
        d += __shfl_xor(d, 2, 64);
        d += __shfl_xor(d, 4, 64);
        d += __shfl_xor(d, 8, 64);
        den += d;
#pragma unroll
        for (int t = 0; t < 6; ++t) {
            int slot = 3 * t + g;
            int sl = slot < 15 ? slot : 15;
            float wg = __shfl(wgl, sl, 64);
            if (slot >= cnt) wg = 0.f;
            a0 = fmaf(wg, __uint_as_float(uu[t] << 16), a0);
            a1 = fmaf(wg, __uint_as_float(uu[t] & 0xffff0000u), a1);
        }
    }
    float t0 = __shfl(a0, (lane + 20) & 63, 64);
    float t1 = __shfl(a0, (lane + 40) & 63, 64);
    float u0 = __shfl(a1, (lane + 20) & 63, 64);
    float u1 = __shfl(a1, (lane + 40) & 63, 64);
    a0 += t0 + t1;
    a1 += u0 + u1;
    if (lane < 20) {
        float inv = 1.f / den;
        float v0 = a0 * inv + b3[c0];
        float v1 = a1 * inv + b3[c0 + 1];
        size_t eoff = (size_t)node * 40 + c0;
        if (*flag) {
            unsigned pk = (unsigned)f2b(v0) | ((unsigned)f2b(v1) << 16);
            *(unsigned*)((unsigned short*)out + eoff) = pk;
        } else {
            *(float2*)((float*)out + eoff) = make_float2(v0, v1);
        }
    }
}

extern "C" void kernel_launch(void* const* d_in, const int* in_sizes, int n_in,
                              void* d_out, int out_size, void* d_ws, size_t ws_size,
                              hipStream_t stream) {
    (void)n_in; (void)out_size; (void)ws_size;
    const int N = in_sizes[0] / 128;
    const int E = in_sizes[1] / 2;
    const int EPN = E + N;
    const int NB = (N + 255) / 256;
    const int CB = (EPN + 255) / 256;
    char* base = (char*)d_ws;
    size_t off = 0;
    auto alloc = [&](size_t bytes) -> char* {
        char* p = base + off;
        off = (off + bytes + 255) & ~(size_t)255;
        return p;
    };
    int* flag = (int*)alloc(4);
    // deg + lookback state: one contiguous zero region (single memset)
    size_t degB = (size_t)N * 4;            // divisible by 8 for N*4 alignment? N*4 % 8 may be 4
    degB = (degB + 7) & ~(size_t)7;
    char* zreg = alloc(degB + (size_t)NB * 8);
    int* deg = (int*)zreg;
    unsigned long long* look = (unsigned long long*)(zreg + degB);
    int* row_ptr = (int*)alloc((size_t)(N + 1) * 4);
    int* pos = (int*)alloc((size_t)N * 4);
    int* csr = (int*)alloc((size_t)EPN * 4);
    float* bnsc1 = (float*)alloc(512); float* bnsh1 = (float*)alloc(512);
    float* bnsc2 = (float*)alloc(512); float* bnsh2 = (float*)alloc(512);
    float* B3f = (float*)alloc(256);
    unsigned short* Wl1 = (unsigned short*)alloc(36864);  // 9 tiles
    unsigned short* Wl2 = (unsigned short*)alloc(36864);  // 9 tiles
    unsigned short* WlR = (unsigned short*)alloc(32768);  // 8 tiles
    unsigned short* Wl3 = (unsigned short*)alloc(12288);  // 3 tiles
    unsigned short* xb = (unsigned short*)alloc((size_t)N * 128 * 2);
    unsigned short* xwb = (unsigned short*)alloc((size_t)N * 128 * 2);  // also xw3
    unsigned short* h1b = (unsigned short*)alloc((size_t)N * 128 * 2);
    unsigned short* resb = (unsigned short*)alloc((size_t)N * 128 * 2); // later h2b
    float* es = (float*)alloc((size_t)N * 4 * 4);   // [node*4+h]
    float* ed = (float*)alloc((size_t)N * 4 * 4);

    const int* ei = (const int*)d_in[1];

    hipMemsetAsync(zreg, 0, degB + (size_t)NB * 8, stream);

    InPtrs ip;
    for (int t = 0; t < 23; t++) ip.p[t] = d_in[t];
    prep_kernel<<<30 + CB + 1024, THREADS, 0, stream>>>(ip, flag, Wl1, Wl2, WlR, Wl3,
                                                        bnsc1, bnsh1, bnsc2, bnsh2,
                                                        B3f, xb, N, ei, deg, E, CB);

    scan_kernel<<<NB, 256, 0, stream>>>(deg, look, row_ptr, pos, N);
    scatter_kernel<<<(EPN + THREADS - 1) / THREADS, THREADS, 0, stream>>>(ei, pos, csr, E, N);

    int gemmGrid = (N + 63) / 64;
    int aggGrid = (N + 3) / 4;

    // layer 1 (W1 + Wres fused GEMM; es/ed via folded MFMA tile)
    gemm_dual<<<gemmGrid, 256, 0, stream>>>((const unsigned short*)d_in[0], xb, flag,
                                            Wl1, WlR, xwb, resb, es, ed, N);
    agg128_fused<<<aggGrid, 256, 0, stream>>>(xwb, es, ed, row_ptr, csr,
                                              bnsc1, bnsh1, resb, h1b, N);
    // layer 2
    gemm_mfma<9, 4, 128><<<gemmGrid, 256, 0, stream>>>(
        h1b, Wl2, xwb, 128, 128, es, ed, N);
    unsigned short* h2b = resb;  // resb free after layer-1 agg
    agg128_fused<<<aggGrid, 256, 0, stream>>>(xwb, es, ed, row_ptr, csr,
                                              bnsc2, bnsh2, h1b, h2b, N);
    // layer 3 (es/ed folded into cols 40,41 of tile 2)
    gemm_mfma<3, 1, 40><<<gemmGrid, 256, 0, stream>>>(
        h2b, Wl3, xwb, 40, 40, es, ed, N);
    agg40_kernel<<<aggGrid, 256, 0, stream>>>(xwb, es, ed, row_ptr, csr, B3f,
                                              d_out, flag, N);
}